// Round 9
// baseline (607.389 us; speedup 1.0000x reference)
//
#include <hip/hip_runtime.h>
#include <stdint.h>

#define B_  128
#define C_  512
#define G_  20
#define K2  4608      // C_*9, conv GEMM K
#define FCK 18432     // C_*36, fc GEMM K

typedef unsigned short u16;
typedef unsigned int   u32;
typedef __attribute__((ext_vector_type(8))) short  short8;
typedef __attribute__((ext_vector_type(4))) short  short4v;
typedef __attribute__((ext_vector_type(4))) float  float4v;

__device__ __forceinline__ u16 f2bf(float f) {
  u32 u = __builtin_bit_cast(u32, f);
  u = (u + 0x7fffu + ((u >> 16) & 1u)) >> 16;   // RNE
  return (u16)u;
}

__device__ __forceinline__ void load_lds16(const void* g, void* l) {
  __builtin_amdgcn_global_load_lds(
      (const __attribute__((address_space(1))) void*)(uintptr_t)g,
      (__attribute__((address_space(3))) void*)(uint32_t)(uintptr_t)l,
      16, 0, 0);
}

#define BAR() __builtin_amdgcn_s_barrier()

// ---------------- landmarks -> integer crop positions ----------------
__global__ void k_pos(const float* __restrict__ y, int* __restrict__ cx, int* __restrict__ cy) {
  int b = blockIdx.x * blockDim.x + threadIdx.x;
  if (b >= B_) return;
  const int   I1[10] = {21,18,19,41,38,49,48,51,61,56};
  const int   I2[10] = {22,25,24,46,43,53,54,57,63,58};
  const float CF[10] = {-0.5f, -1.0f/3.0f, 1.0f/3.0f, 1.0f, 0.f,0.f,0.f,0.f,0.f, 0.5f};
  const float* yb = y + b * 136;
  float ruler = fabsf(yb[2*39] - yb[2*42]);
  for (int j = 0; j < 10; ++j) {
    float off = ruler * CF[j];
    float vx1 = yb[2*I1[j]];
    float vy1 = yb[2*I1[j]+1] + off;
    float vx2 = yb[2*I2[j]];
    float vy2 = yb[2*I2[j]+1] + off;
    int px1 = (int)(vx1 * 0.0625f); px1 = min(max(px1,1),12);
    int py1 = (int)(vy1 * 0.0625f); py1 = min(max(py1,1),12);
    int px2 = (int)(vx2 * 0.0625f); px2 = min(max(px2,1),12);
    int py2 = (int)(vy2 * 0.0625f); py2 = min(max(py2,1),12);
    cx[b*20 + 2*j]   = px1;  cx[b*20 + 2*j+1] = px2;
    cy[b*20 + 2*j]   = py1;  cy[b*20 + 2*j+1] = py2;
  }
}

// ---------------- fused pre-pass: conv_w convert + crop/upsample ----------------
__global__ void __launch_bounds__(256) k_pre(const float* __restrict__ w, u16* __restrict__ wb,
                                             const float* __restrict__ x,
                                             const int* __restrict__ cx, const int* __restrict__ cy,
                                             u16* __restrict__ up3) {
  __shared__ __align__(16) char smraw[4 * 4608 * 2];   // 36.9 KB, shared by both paths
  int tid = threadIdx.x;
  if (blockIdx.x < 2560) {
    u16* lds = (u16*)smraw;
    int ob = blockIdx.x * 4;
    const float4* in4 = (const float4*)(w + (size_t)ob * 4608);
    #pragma unroll
    for (int r = 0; r < 18; ++r) {
      int fi = r * 256 + tid;                       // 0..4607 float4s
      float4 v = in4[fi];
      u16 q[4] = { f2bf(v.x), f2bf(v.y), f2bf(v.z), f2bf(v.w) };
      *(short4v*)&lds[fi * 4] = *(short4v*)q;
    }
    __syncthreads();
    #pragma unroll
    for (int r = 0; r < 9; ++r) {
      int wi = r * 256 + tid;                       // 0..2303 = 4o x 9t x 64ci8
      int ci0 = (wi & 63) * 8;
      int t   = (wi >> 6) % 9;
      int o   = wi / 576;
      u16 vals[8];
      #pragma unroll
      for (int j = 0; j < 8; ++j) vals[j] = lds[o * 4608 + (ci0 + j) * 9 + t];
      *(short8*)(wb + ((size_t)(ob + o)) * K2 + t * 512 + ci0) = *(short8*)vals;
    }
  } else {
    float (*crop)[3][C_] = (float(*)[3][C_])smraw;   // [r][s][ci], 18.4 KB
    int bg = blockIdx.x - 2560;        // b*20+g
    int b = bg / 20, g = bg % 20;
    int X = cx[bg] - 1, Y = cy[bg] - 1;
    const float* xb = x + (size_t)b * (C_*14*14);
    for (int it = 0; it < 6; ++it) {
      int idx = it*256 + tid;          // 1536 = 512*3
      int r = idx >> 9, ci = idx & 511;
      const float* srow = xb + ci*196 + (Y + r)*14 + X;
      crop[r][0][ci] = srow[0];
      crop[r][1][ci] = srow[1];
      crop[r][2][ci] = srow[2];
    }
    __syncthreads();
    const int   R0[6] = {0,0,0,1,1,1};
    const float WA[6] = {1.f, .75f, .25f, .75f, .25f, 0.f};
    u16* dstbase = up3 + ((size_t)g*B_ + b) * 64 * C_;
    for (int it = 0; it < 16; ++it) {
      int cidx = it*256 + tid;         // 4096 chunks of 8 ci
      int pp = cidx >> 6;
      int c8 = (cidx & 63) * 8;
      int ph = pp >> 3, pw = pp & 7;
      u16 outv[8];
      if (ph == 0 || ph == 7 || pw == 0 || pw == 7) {
        #pragma unroll
        for (int j = 0; j < 8; ++j) outv[j] = 0;
      } else {
        int oh = ph - 1, ow = pw - 1;
        int r0 = R0[oh]; float wy0 = WA[oh], wy1 = 1.f - WA[oh];
        int s0 = R0[ow]; float wx0 = WA[ow], wx1 = 1.f - WA[ow];
        #pragma unroll
        for (int j = 0; j < 8; ++j) {
          int ci = c8 + j;
          float v = wy0*(wx0*crop[r0][s0][ci]   + wx1*crop[r0][s0+1][ci])
                  + wy1*(wx0*crop[r0+1][s0][ci] + wx1*crop[r0+1][s0+1][ci]);
          outv[j] = f2bf(v);
        }
      }
      *(short8*)(dstbase + (size_t)pp*C_ + c8) = *(short8*)outv;
    }
  }
}

// ---------------- grouped conv implicit GEMM, 8-phase / 1-barrier schedule ----------------
// Blocks [0,720): GEMM (XCD-chunked). Blocks [720,2160): independent fc_w->bf16
// conversion (tail-filler overlap; no ordering assumption — pure perf).
// 1 barrier per phase (WAR audit in round-9 notes): every stage-issue has >=1 full
// barrier after the last reader's consumption; stageA(t+3,1) moved post-BAR(ph8).
// vmcnt: ph4-end (6), ph8-end (8) — unchanged derivation.
__global__ void __launch_bounds__(512, 2) k_conv(const u16* __restrict__ wb,
                                                 const u16* __restrict__ up3,
                                                 const float* __restrict__ conv_b,
                                                 u16* __restrict__ feat,
                                                 const float* __restrict__ fw,
                                                 u16* __restrict__ wfcb) {
  __shared__ __align__(16) u16 As[2 * 256 * 64];   // 64 KB (2 dbuf)
  __shared__ __align__(16) u16 Bs[2 * 256 * 64];   // 64 KB
  int bid = blockIdx.x;
  int tid = threadIdx.x;

  if (bid >= 720) {
    // ---- fc_w f32 [g][i=co*36+pix][o:150] -> bf16 wfcb[g][o:160][i'=pix*512+co] ----
    u16* tile = (u16*)As;                       // [64][161] u16 = 20.6 KB
    int cid = bid - 720;                        // 0..1439
    int g = cid / 72, ch = cid - g * 72;        // ch: 256-col chunk
    for (int cc = 0; cc < 4; ++cc) {
      int c = ch * 256 + cc * 64;               // i'-base, multiple of 64
      int pix = c >> 9, co0 = c & 511;
      if (cc) __syncthreads();
      for (int i2 = 0; i2 < 19; ++i2) {
        int f = i2 * 512 + tid;                 // 64 rows x 150 o
        if (f < 9600) {
          int q = f / 150, o = f - q * 150;
          tile[q * 161 + o] =
              f2bf(fw[((size_t)g * FCK + (size_t)(co0 + q) * 36 + pix) * 150 + o]);
        }
      }
      __syncthreads();
      for (int i2 = 0; i2 < 3; ++i2) {
        int wi = i2 * 512 + tid;                // 160 o x 8 q-chunks
        if (wi < 1280) {
          int o = wi >> 3, qc = (wi & 7) * 8;
          u16 vals[8];
          if (o < 150) {
            #pragma unroll
            for (int j = 0; j < 8; ++j) vals[j] = tile[(qc + j) * 161 + o];
          } else {
            #pragma unroll
            for (int j = 0; j < 8; ++j) vals[j] = 0;
          }
          *(short8*)(wfcb + ((size_t)(g * 160 + o)) * FCK + c + qc) = *(short8*)vals;
        }
      }
    }
    return;
  }

  int lid = (bid & 7) * 90 + (bid >> 3);    // bijective: 720 = 8*90
  int mt = lid & 1;
  int nt = (lid >> 1) % 18;
  int g  = lid / 36;
  int lane = tid & 63;
  int w = tid >> 6;                          // 8 waves
  int wr = w >> 2, wc = w & 3;               // 2M x 4N
  int l15 = lane & 15, l4 = lane >> 4;

  int rl0 = tid >> 3, sl0 = tid & 7;
  const u16* srcA0 = wb + (size_t)(g*512 + mt*256 + rl0) * K2 + (sl0 ^ (rl0 & 7)) * 8;
  const u16* srcB[2][2];
  #pragma unroll
  for (int h = 0; h < 2; ++h)
    #pragma unroll
    for (int j = 0; j < 2; ++j) {
      int rl = j * 64 + rl0;
      int n  = nt * 256 + h * 128 + rl;
      unsigned bb = (unsigned)n / 36u;
      unsigned pix = (unsigned)n % 36u;
      int pixA = (int)(pix / 6u) * 8 + (int)(pix % 6u);
      srcB[h][j] = up3 + (((size_t)g*B_ + bb)*64 + pixA) * C_ + (sl0 ^ (rl0 & 7)) * 8;
    }

  auto stageA = [&](int st, int h) {
    if (st >= 72) return;
    int db = st & 1;
    size_t ko = (size_t)st * 64;
    #pragma unroll
    for (int j = 0; j < 2; ++j)
      load_lds16(srcA0 + (size_t)(h*128 + j*64) * K2 + ko,
                 (char*)As + db*32768 + h*16384 + (j*512 + tid)*16);
  };
  auto stageB = [&](int st, int h) {
    if (st >= 72) return;
    int db = st & 1;
    int t9 = st >> 3;
    size_t ko = (size_t)((t9/3)*8 + (t9%3)) * C_ + (size_t)(st & 7) * 64;
    #pragma unroll
    for (int j = 0; j < 2; ++j)
      load_lds16(srcB[h][j] + ko,
                 (char*)Bs + db*32768 + h*16384 + (j*512 + tid)*16);
  };

  auto ldfrag = [&](const char* base, int row, int kb) -> short8 {
    int cb = (kb*64 + l4*16) ^ ((row & 7) << 4);
    return *(const short8*)(base + row*128 + cb);
  };

  float4v acc[8][4];
  #pragma unroll
  for (int mi = 0; mi < 8; ++mi)
    #pragma unroll
    for (int nj = 0; nj < 4; ++nj) acc[mi][nj] = (float4v){0.f,0.f,0.f,0.f};

  stageB(0,0); stageB(0,1); stageA(0,0); stageA(0,1);
  stageB(1,0); stageB(1,1); stageA(1,0); stageA(1,1);
  asm volatile("s_waitcnt vmcnt(8)" ::: "memory");
  BAR();

  short8 aF[4][2], b01[2][2], b23[2][2];

#define LDA_HALF(BASE, MH)                                        \
  _Pragma("unroll") for (int mi = 0; mi < 4; ++mi)                \
    _Pragma("unroll") for (int kb = 0; kb < 2; ++kb)              \
      aF[mi][kb] = ldfrag(BASE, wr*128 + ((MH)*4 + mi)*16 + l15, kb);
#define LDB_HALF(BASE, NH, DST)                                   \
  _Pragma("unroll") for (int nj = 0; nj < 2; ++nj)                \
    _Pragma("unroll") for (int kb = 0; kb < 2; ++kb)              \
      DST[nj][kb] = ldfrag(BASE, wc*64 + ((NH)*2 + nj)*16 + l15, kb);
#define MFMA_QUAD(BF, QM, QN)                                     \
  __builtin_amdgcn_s_setprio(1);                                  \
  _Pragma("unroll") for (int kb = 0; kb < 2; ++kb)                \
    _Pragma("unroll") for (int mi = 0; mi < 4; ++mi)              \
      _Pragma("unroll") for (int nj = 0; nj < 2; ++nj)            \
        acc[(QM)*4+mi][(QN)*2+nj] = __builtin_amdgcn_mfma_f32_16x16x32_bf16( \
            aF[mi][kb], BF[nj][kb], acc[(QM)*4+mi][(QN)*2+nj], 0, 0, 0);     \
  __builtin_amdgcn_s_setprio(0);

  for (int it = 0; it < 36; ++it) {
    int t0 = 2 * it;
    const char* A0 = (const char*)As;
    const char* B0 = (const char*)Bs;
    const char* A1 = (const char*)As + 32768;
    const char* B1 = (const char*)Bs + 32768;
    // ---- ph1 ----
    LDA_HALF(A0, 0); LDB_HALF(B0, 0, b01);
    BAR(); MFMA_QUAD(b01, 0, 0);
    // ---- ph2 ----
    LDB_HALF(B0, 1, b23);
    BAR(); MFMA_QUAD(b23, 0, 1);
    // ---- ph3 ----
    LDA_HALF(A0, 1);
    stageB(t0 + 2, 0);
    BAR(); MFMA_QUAD(b01, 1, 0);
    // ---- ph4 ----
    stageB(t0 + 2, 1); stageA(t0 + 2, 0);
    BAR(); MFMA_QUAD(b23, 1, 1);
    if (it < 35) { asm volatile("s_waitcnt vmcnt(6)" ::: "memory"); }
    else         { asm volatile("s_waitcnt vmcnt(0)" ::: "memory"); }
    BAR();
    // ---- ph5 ----
    LDA_HALF(A1, 0); LDB_HALF(B1, 0, b01);
    stageA(t0 + 2, 1);
    BAR(); MFMA_QUAD(b01, 0, 0);
    // ---- ph6 ----
    LDB_HALF(B1, 1, b23);
    BAR(); MFMA_QUAD(b23, 0, 1);
    // ---- ph7 ----
    LDA_HALF(A1, 1);
    stageB(t0 + 3, 0);
    BAR(); MFMA_QUAD(b01, 1, 0);
    // ---- ph8 ----
    stageB(t0 + 3, 1); stageA(t0 + 3, 0);
    BAR();
    stageA(t0 + 3, 1);       // post-BAR: ph7's A1h1 readers consumed pre-arrival
    MFMA_QUAD(b23, 1, 1);
    asm volatile("s_waitcnt vmcnt(8)" ::: "memory");
    BAR();
  }
#undef LDA_HALF
#undef LDB_HALF
#undef MFMA_QUAD

  // ---- epilogue: bias + relu -> feat[g][b][pix*512+co], short4 stores ----
  float bias[8][4];
  #pragma unroll
  for (int mi = 0; mi < 8; ++mi)
    #pragma unroll
    for (int r = 0; r < 4; ++r)
      bias[mi][r] = conv_b[g*512 + mt*256 + wr*128 + mi*16 + l4*4 + r];
  #pragma unroll
  for (int nj = 0; nj < 4; ++nj) {
    int n = nt*256 + wc*64 + nj*16 + l15;
    unsigned bb = (unsigned)n / 36u;
    unsigned pix = (unsigned)n % 36u;
    size_t base = ((size_t)g*B_ + bb)*FCK + (size_t)pix*512;
    #pragma unroll
    for (int mi = 0; mi < 8; ++mi) {
      int co0 = mt*256 + wr*128 + mi*16 + l4*4;
      u16 q[4];
      #pragma unroll
      for (int r = 0; r < 4; ++r)
        q[r] = f2bf(fmaxf(acc[mi][nj][r] + bias[mi][r], 0.f));
      *(short4v*)(feat + base + co0) = *(short4v*)q;
    }
  }
}

// ---------------- FC: per-group [128 x 18432] x [18432 x 160], split-K ----------------
// B from bf16 wfcb (load_lds16, round-3 pattern) when available; else inline f32.
__global__ void __launch_bounds__(256) k_fc(const u16* __restrict__ feat,
                                            const float* __restrict__ fw,
                                            const u16* __restrict__ wfcb,
                                            float* __restrict__ accum) {
  __shared__ __align__(16) u16 As[128*64];   // 16 KB
  __shared__ __align__(16) u16 Bs[160*64];   // 20 KB
  int sp = blockIdx.x;   // 0..31 k-split
  int g  = blockIdx.y;
  int tid = threadIdx.x;
  int lane = tid & 63, w = tid >> 6;
  int wr = w >> 1, wc = w & 1;
  int rl = lane >> 3, s = lane & 7;
  int l15 = lane & 15, l4 = lane >> 4;

  const u16* gA[4]; u16* lA[4];
  #pragma unroll
  for (int i = 0; i < 4; ++i) {
    int r = w*32 + i*8 + rl;
    int c = s ^ (r & 7);
    gA[i] = feat + ((size_t)g*B_ + r)*FCK + c*8;
    lA[i] = (u16*)As + (w*32 + i*8) * 64;
  }
  const u16* gB[5]; u16* lB[5];
  bool useW = (wfcb != nullptr);
  #pragma unroll
  for (int i = 0; i < 5; ++i) {
    int r = w*40 + i*8 + rl;
    int c = s ^ (r & 7);
    gB[i] = useW ? (wfcb + ((size_t)(g*160 + r))*FCK + c*8) : nullptr;
    lB[i] = (u16*)Bs + (w*40 + i*8) * 64;
  }

  float4v acc[4][5];
  #pragma unroll
  for (int mi = 0; mi < 4; ++mi)
    #pragma unroll
    for (int nj = 0; nj < 5; ++nj) acc[mi][nj] = (float4v){0.f,0.f,0.f,0.f};

  int kbase = sp * 576;
  for (int stp = 0; stp < 9; ++stp) {
    int i0 = kbase + stp * 64;
    __syncthreads();
    #pragma unroll
    for (int i = 0; i < 4; ++i) load_lds16(gA[i] + i0, lA[i]);
    if (useW) {
      #pragma unroll
      for (int i = 0; i < 5; ++i) load_lds16(gB[i] + i0, lB[i]);
    } else {
      int pix = i0 >> 9;
      int cobase = i0 & 511;
      #pragma unroll
      for (int bit = 0; bit < 5; ++bit) {
        int idx = bit * 256 + tid;
        int il8 = idx / 160;
        int o   = idx - il8 * 160;
        u16 vals[8];
        if (o < 150) {
          const float* src = fw + ((size_t)g * FCK + (size_t)(cobase + il8 * 8) * 36 + pix) * 150 + o;
          #pragma unroll
          for (int j = 0; j < 8; ++j) vals[j] = f2bf(src[(size_t)j * 5400]);
        } else {
          #pragma unroll
          for (int j = 0; j < 8; ++j) vals[j] = 0;
        }
        *(short8*)((char*)Bs + o * 128 + ((il8 ^ (o & 7)) * 16)) = *(short8*)vals;
      }
    }
    __syncthreads();

    short8 a[4][2], bf[5][2];
    #pragma unroll
    for (int kb = 0; kb < 2; ++kb) {
      #pragma unroll
      for (int mi = 0; mi < 4; ++mi) {
        int row = wr*64 + mi*16 + l15;
        int cb  = (kb*64 + l4*16) ^ ((row & 7) << 4);
        a[mi][kb] = *(const short8*)((const char*)As + row*128 + cb);
      }
      #pragma unroll
      for (int nj = 0; nj < 5; ++nj) {
        int row = wc*80 + nj*16 + l15;
        int cb  = (kb*64 + l4*16) ^ ((row & 7) << 4);
        bf[nj][kb] = *(const short8*)((const char*)Bs + row*128 + cb);
      }
    }
    #pragma unroll
    for (int kb = 0; kb < 2; ++kb)
      #pragma unroll
      for (int mi = 0; mi < 4; ++mi)
        #pragma unroll
        for (int nj = 0; nj < 5; ++nj)
          acc[mi][nj] = __builtin_amdgcn_mfma_f32_16x16x32_bf16(
              a[mi][kb], bf[nj][kb], acc[mi][nj], 0, 0, 0);
  }

  #pragma unroll
  for (int mi = 0; mi < 4; ++mi)
    #pragma unroll
    for (int r = 0; r < 4; ++r) {
      int brow = wr*64 + mi*16 + l4*4 + r;
      #pragma unroll
      for (int nj = 0; nj < 5; ++nj) {
        int o = wc*80 + nj*16 + l15;
        atomicAdd(&accum[((size_t)brow*20 + g)*160 + o], acc[mi][nj][r]);
      }
    }
}

__global__ void k_final(const float* __restrict__ accum, const float* __restrict__ fcb,
                        float* __restrict__ out) {
  int idx = blockIdx.x * 256 + threadIdx.x;     // 128*3000
  if (idx >= B_*3000) return;
  unsigned b = (unsigned)idx / 3000u;
  unsigned rem = (unsigned)idx % 3000u;
  unsigned g = rem / 150u, o = rem % 150u;
  out[idx] = fmaxf(accum[((size_t)b*20 + g)*160 + o] + fcb[g*150 + o], 0.f);
}

extern "C" void kernel_launch(void* const* d_in, const int* in_sizes, int n_in,
                              void* d_out, int out_size, void* d_ws, size_t ws_size,
                              hipStream_t stream) {
  const float* x      = (const float*)d_in[0];
  const float* y      = (const float*)d_in[1];
  const float* conv_w = (const float*)d_in[2];
  const float* conv_b = (const float*)d_in[3];
  const float* fc_w   = (const float*)d_in[4];
  const float* fc_b   = (const float*)d_in[5];
  float* out = (float*)d_out;

  char* ws = (char*)d_ws;
  size_t off = 0;
  u16* Wb   = (u16*)(ws + off); off += (size_t)10240 * K2 * 2;        // 94.4 MB
  u16* up3  = (u16*)(ws + off); off += (size_t)G_ * B_ * 64 * C_ * 2; // 167.8 MB
  u16* feat = (u16*)(ws + off); off += (size_t)G_ * B_ * FCK * 2;     // 94.4 MB
  float* accum = (float*)(ws + off); off += (size_t)B_ * G_ * 160 * 4;// 1.6 MB
  int* cx = (int*)(ws + off); off += B_ * G_ * 4;
  int* cy = (int*)(ws + off); off += B_ * G_ * 4;
  u16* Wfcb = (u16*)(ws + off); off += (size_t)G_ * 160 * FCK * 2;    // 118 MB
  bool fuse = (ws_size >= off);   // 476.1 MB needed for the bf16-fc path

  k_pos<<<1, 128, 0, stream>>>(y, cx, cy);
  hipMemsetAsync(accum, 0, (size_t)B_ * G_ * 160 * 4, stream);
  k_pre<<<5120, 256, 0, stream>>>(conv_w, Wb, x, cx, cy, up3);
  k_conv<<<fuse ? 2160 : 720, 512, 0, stream>>>(Wb, up3, conv_b, feat, fc_w,
                                                fuse ? Wfcb : (u16*)nullptr);
  k_fc<<<dim3(32, 20), 256, 0, stream>>>(feat, fc_w, fuse ? Wfcb : (u16*)nullptr, accum);
  k_final<<<(B_*3000 + 255)/256, 256, 0, stream>>>(accum, fc_b, out);
}

// Round 10
// 559.256 us; speedup vs baseline: 1.0861x; 1.0861x over previous
//
#include <hip/hip_runtime.h>
#include <stdint.h>

#define B_  128
#define C_  512
#define G_  20
#define K2  4608      // C_*9, conv GEMM K
#define FCK 18432     // C_*36, fc GEMM K

typedef unsigned short u16;
typedef unsigned int   u32;
typedef __attribute__((ext_vector_type(8))) short  short8;
typedef __attribute__((ext_vector_type(4))) short  short4v;
typedef __attribute__((ext_vector_type(4))) float  float4v;

__device__ __forceinline__ u16 f2bf(float f) {
  u32 u = __builtin_bit_cast(u32, f);
  u = (u + 0x7fffu + ((u >> 16) & 1u)) >> 16;   // RNE
  return (u16)u;
}

__device__ __forceinline__ float bf2f(u16 h) {
  u32 u = ((u32)h) << 16;
  return __builtin_bit_cast(float, u);
}

__device__ __forceinline__ void load_lds16(const void* g, void* l) {
  __builtin_amdgcn_global_load_lds(
      (const __attribute__((address_space(1))) void*)(uintptr_t)g,
      (__attribute__((address_space(3))) void*)(uint32_t)(uintptr_t)l,
      16, 0, 0);
}

#define BAR() __builtin_amdgcn_s_barrier()

// ---------------- landmarks -> integer crop positions ----------------
__global__ void k_pos(const float* __restrict__ y, int* __restrict__ cx, int* __restrict__ cy) {
  int b = blockIdx.x * blockDim.x + threadIdx.x;
  if (b >= B_) return;
  const int   I1[10] = {21,18,19,41,38,49,48,51,61,56};
  const int   I2[10] = {22,25,24,46,43,53,54,57,63,58};
  const float CF[10] = {-0.5f, -1.0f/3.0f, 1.0f/3.0f, 1.0f, 0.f,0.f,0.f,0.f,0.f, 0.5f};
  const float* yb = y + b * 136;
  float ruler = fabsf(yb[2*39] - yb[2*42]);
  for (int j = 0; j < 10; ++j) {
    float off = ruler * CF[j];
    float vx1 = yb[2*I1[j]];
    float vy1 = yb[2*I1[j]+1] + off;
    float vx2 = yb[2*I2[j]];
    float vy2 = yb[2*I2[j]+1] + off;
    int px1 = (int)(vx1 * 0.0625f); px1 = min(max(px1,1),12);
    int py1 = (int)(vy1 * 0.0625f); py1 = min(max(py1,1),12);
    int px2 = (int)(vx2 * 0.0625f); px2 = min(max(px2,1),12);
    int py2 = (int)(vy2 * 0.0625f); py2 = min(max(py2,1),12);
    cx[b*20 + 2*j]   = px1;  cx[b*20 + 2*j+1] = px2;
    cy[b*20 + 2*j]   = py1;  cy[b*20 + 2*j+1] = py2;
  }
}

// ---------------- pre-pass 1: conv_w convert + x NHWC transpose ----------------
// blocks [0,2560):  conv_w f32 [o][ci][t] -> bf16 Wb[o][t*512+ci] (4 o per block)
// blocks [2560,3584): x f32 [b][ci][p] -> bf16 xT[b][p][ci] (LDS transpose,
//   coalesced reads AND writes; kills the 16x line amplification of the old
//   strided crop loads). Both halves independent -> overlap in one dispatch.
__global__ void __launch_bounds__(256) k_pre1(const float* __restrict__ w, u16* __restrict__ wb,
                                              const float* __restrict__ x, u16* __restrict__ xT) {
  __shared__ __align__(16) char smraw[4 * 4608 * 2];   // 36.9 KB
  int tid = threadIdx.x;
  if (blockIdx.x < 2560) {
    u16* lds = (u16*)smraw;
    int ob = blockIdx.x * 4;
    const float4* in4 = (const float4*)(w + (size_t)ob * 4608);
    #pragma unroll
    for (int r = 0; r < 18; ++r) {
      int fi = r * 256 + tid;                       // 0..4607 float4s
      float4 v = in4[fi];
      u16 q[4] = { f2bf(v.x), f2bf(v.y), f2bf(v.z), f2bf(v.w) };
      *(short4v*)&lds[fi * 4] = *(short4v*)q;
    }
    __syncthreads();
    #pragma unroll
    for (int r = 0; r < 9; ++r) {
      int wi = r * 256 + tid;                       // 0..2303 = 4o x 9t x 64ci8
      int ci0 = (wi & 63) * 8;
      int t   = (wi >> 6) % 9;
      int o   = wi / 576;
      u16 vals[8];
      #pragma unroll
      for (int j = 0; j < 8; ++j) vals[j] = lds[o * 4608 + (ci0 + j) * 9 + t];
      *(short8*)(wb + ((size_t)(ob + o)) * K2 + t * 512 + ci0) = *(short8*)vals;
    }
  } else {
    // transpose one (b, 64-ci chunk): read [64][196] coalesced in p,
    // write [196][64] coalesced in ci (short8).
    u16* lds = (u16*)smraw;                         // [64][197] pad
    int cid = blockIdx.x - 2560;                    // 0..1023
    int b = cid >> 3, cic = (cid & 7) * 64;
    const float* src = x + ((size_t)b * C_ + cic) * 196;
    #pragma unroll
    for (int it = 0; it < 49; ++it) {
      int idx = it * 256 + tid;                     // 64*196
      int ci = idx / 196, p = idx - ci * 196;
      lds[ci * 197 + p] = f2bf(src[(size_t)ci * 196 + p]);
    }
    __syncthreads();
    u16* dst = xT + (size_t)b * 196 * C_ + cic;
    #pragma unroll
    for (int it = 0; it < 7; ++it) {
      int idx = it * 256 + tid;                     // 196*8 = 1568 chunks
      if (idx < 1568) {
        int p = idx >> 3, c8 = (idx & 7) * 8;
        u16 vals[8];
        #pragma unroll
        for (int j = 0; j < 8; ++j) vals[j] = lds[(c8 + j) * 197 + p];
        *(short8*)(dst + (size_t)p * C_ + c8) = *(short8*)vals;
      }
    }
  }
}

// ---------------- pre-pass 2: crop + bilinear 2x upsample from xT ----------------
// reads 9 contiguous 1-KB runs per crop (vs 3x512 scattered 12B rows before).
__global__ void __launch_bounds__(256) k_pre2(const u16* __restrict__ xT,
                                              const int* __restrict__ cx,
                                              const int* __restrict__ cy,
                                              u16* __restrict__ up3) {
  __shared__ float crop[3][3][C_];   // [r][s][ci], 18.4 KB
  int bg = blockIdx.x;               // b*20+g
  int b = bg / 20, g = bg % 20;
  int X = cx[bg] - 1, Y = cy[bg] - 1;
  int tid = threadIdx.x;
  const u16* xb = xT + (size_t)b * 196 * C_;
  #pragma unroll
  for (int it = 0; it < 3; ++it) {
    int idx = it * 256 + tid;        // 576 = 9 pos x 64 chunks
    if (idx < 576) {
      int pos = idx >> 6;            // r*3+s
      int r = pos / 3, s = pos - r * 3;
      int c8 = (idx & 63) * 8;
      short8 v = *(const short8*)(xb + (size_t)((Y + r) * 14 + X + s) * C_ + c8);
      #pragma unroll
      for (int j = 0; j < 8; ++j) crop[r][s][c8 + j] = bf2f((u16)v[j]);
    }
  }
  __syncthreads();
  const int   R0[6] = {0,0,0,1,1,1};
  const float WA[6] = {1.f, .75f, .25f, .75f, .25f, 0.f};
  u16* dstbase = up3 + ((size_t)g*B_ + b) * 64 * C_;
  for (int it = 0; it < 16; ++it) {
    int cidx = it*256 + tid;         // 4096 chunks of 8 ci
    int pp = cidx >> 6;
    int c8 = (cidx & 63) * 8;
    int ph = pp >> 3, pw = pp & 7;
    u16 outv[8];
    if (ph == 0 || ph == 7 || pw == 0 || pw == 7) {
      #pragma unroll
      for (int j = 0; j < 8; ++j) outv[j] = 0;
    } else {
      int oh = ph - 1, ow = pw - 1;
      int r0 = R0[oh]; float wy0 = WA[oh], wy1 = 1.f - WA[oh];
      int s0 = R0[ow]; float wx0 = WA[ow], wx1 = 1.f - WA[ow];
      #pragma unroll
      for (int j = 0; j < 8; ++j) {
        int ci = c8 + j;
        float v = wy0*(wx0*crop[r0][s0][ci]   + wx1*crop[r0][s0+1][ci])
                + wy1*(wx0*crop[r0+1][s0][ci] + wx1*crop[r0+1][s0+1][ci]);
        outv[j] = f2bf(v);
      }
    }
    *(short8*)(dstbase + (size_t)pp*C_ + c8) = *(short8*)outv;
  }
}

// ---------------- grouped conv implicit GEMM, 8-phase / 1-barrier schedule ----------------
// (round-9 GEMM loop, reverted to pure-GEMM 720-block dispatch)
__global__ void __launch_bounds__(512, 2) k_conv(const u16* __restrict__ wb,
                                                 const u16* __restrict__ up3,
                                                 const float* __restrict__ conv_b,
                                                 u16* __restrict__ feat) {
  __shared__ __align__(16) u16 As[2 * 256 * 64];   // 64 KB (2 dbuf)
  __shared__ __align__(16) u16 Bs[2 * 256 * 64];   // 64 KB
  int bid = blockIdx.x;
  int tid = threadIdx.x;
  int lid = (bid & 7) * 90 + (bid >> 3);    // bijective: 720 = 8*90
  int mt = lid & 1;
  int nt = (lid >> 1) % 18;
  int g  = lid / 36;
  int lane = tid & 63;
  int w = tid >> 6;                          // 8 waves
  int wr = w >> 2, wc = w & 3;               // 2M x 4N
  int l15 = lane & 15, l4 = lane >> 4;

  int rl0 = tid >> 3, sl0 = tid & 7;
  const u16* srcA0 = wb + (size_t)(g*512 + mt*256 + rl0) * K2 + (sl0 ^ (rl0 & 7)) * 8;
  const u16* srcB[2][2];
  #pragma unroll
  for (int h = 0; h < 2; ++h)
    #pragma unroll
    for (int j = 0; j < 2; ++j) {
      int rl = j * 64 + rl0;
      int n  = nt * 256 + h * 128 + rl;
      unsigned bb = (unsigned)n / 36u;
      unsigned pix = (unsigned)n % 36u;
      int pixA = (int)(pix / 6u) * 8 + (int)(pix % 6u);
      srcB[h][j] = up3 + (((size_t)g*B_ + bb)*64 + pixA) * C_ + (sl0 ^ (rl0 & 7)) * 8;
    }

  auto stageA = [&](int st, int h) {
    if (st >= 72) return;
    int db = st & 1;
    size_t ko = (size_t)st * 64;
    #pragma unroll
    for (int j = 0; j < 2; ++j)
      load_lds16(srcA0 + (size_t)(h*128 + j*64) * K2 + ko,
                 (char*)As + db*32768 + h*16384 + (j*512 + tid)*16);
  };
  auto stageB = [&](int st, int h) {
    if (st >= 72) return;
    int db = st & 1;
    int t9 = st >> 3;
    size_t ko = (size_t)((t9/3)*8 + (t9%3)) * C_ + (size_t)(st & 7) * 64;
    #pragma unroll
    for (int j = 0; j < 2; ++j)
      load_lds16(srcB[h][j] + ko,
                 (char*)Bs + db*32768 + h*16384 + (j*512 + tid)*16);
  };

  auto ldfrag = [&](const char* base, int row, int kb) -> short8 {
    int cb = (kb*64 + l4*16) ^ ((row & 7) << 4);
    return *(const short8*)(base + row*128 + cb);
  };

  float4v acc[8][4];
  #pragma unroll
  for (int mi = 0; mi < 8; ++mi)
    #pragma unroll
    for (int nj = 0; nj < 4; ++nj) acc[mi][nj] = (float4v){0.f,0.f,0.f,0.f};

  stageB(0,0); stageB(0,1); stageA(0,0); stageA(0,1);
  stageB(1,0); stageB(1,1); stageA(1,0); stageA(1,1);
  asm volatile("s_waitcnt vmcnt(8)" ::: "memory");
  BAR();

  short8 aF[4][2], b01[2][2], b23[2][2];

#define LDA_HALF(BASE, MH)                                        \
  _Pragma("unroll") for (int mi = 0; mi < 4; ++mi)                \
    _Pragma("unroll") for (int kb = 0; kb < 2; ++kb)              \
      aF[mi][kb] = ldfrag(BASE, wr*128 + ((MH)*4 + mi)*16 + l15, kb);
#define LDB_HALF(BASE, NH, DST)                                   \
  _Pragma("unroll") for (int nj = 0; nj < 2; ++nj)                \
    _Pragma("unroll") for (int kb = 0; kb < 2; ++kb)              \
      DST[nj][kb] = ldfrag(BASE, wc*64 + ((NH)*2 + nj)*16 + l15, kb);
#define MFMA_QUAD(BF, QM, QN)                                     \
  __builtin_amdgcn_s_setprio(1);                                  \
  _Pragma("unroll") for (int kb = 0; kb < 2; ++kb)                \
    _Pragma("unroll") for (int mi = 0; mi < 4; ++mi)              \
      _Pragma("unroll") for (int nj = 0; nj < 2; ++nj)            \
        acc[(QM)*4+mi][(QN)*2+nj] = __builtin_amdgcn_mfma_f32_16x16x32_bf16( \
            aF[mi][kb], BF[nj][kb], acc[(QM)*4+mi][(QN)*2+nj], 0, 0, 0);     \
  __builtin_amdgcn_s_setprio(0);

  for (int it = 0; it < 36; ++it) {
    int t0 = 2 * it;
    const char* A0 = (const char*)As;
    const char* B0 = (const char*)Bs;
    const char* A1 = (const char*)As + 32768;
    const char* B1 = (const char*)Bs + 32768;
    // ---- ph1 ----
    LDA_HALF(A0, 0); LDB_HALF(B0, 0, b01);
    BAR(); MFMA_QUAD(b01, 0, 0);
    // ---- ph2 ----
    LDB_HALF(B0, 1, b23);
    BAR(); MFMA_QUAD(b23, 0, 1);
    // ---- ph3 ----
    LDA_HALF(A0, 1);
    stageB(t0 + 2, 0);
    BAR(); MFMA_QUAD(b01, 1, 0);
    // ---- ph4 ----
    stageB(t0 + 2, 1); stageA(t0 + 2, 0);
    BAR(); MFMA_QUAD(b23, 1, 1);
    if (it < 35) { asm volatile("s_waitcnt vmcnt(6)" ::: "memory"); }
    else         { asm volatile("s_waitcnt vmcnt(0)" ::: "memory"); }
    BAR();
    // ---- ph5 ----
    LDA_HALF(A1, 0); LDB_HALF(B1, 0, b01);
    stageA(t0 + 2, 1);
    BAR(); MFMA_QUAD(b01, 0, 0);
    // ---- ph6 ----
    LDB_HALF(B1, 1, b23);
    BAR(); MFMA_QUAD(b23, 0, 1);
    // ---- ph7 ----
    LDA_HALF(A1, 1);
    stageB(t0 + 3, 0);
    BAR(); MFMA_QUAD(b01, 1, 0);
    // ---- ph8 ----
    stageB(t0 + 3, 1); stageA(t0 + 3, 0);
    BAR();
    stageA(t0 + 3, 1);       // post-BAR: ph7's A1h1 readers consumed pre-arrival
    MFMA_QUAD(b23, 1, 1);
    asm volatile("s_waitcnt vmcnt(8)" ::: "memory");
    BAR();
  }
#undef LDA_HALF
#undef LDB_HALF
#undef MFMA_QUAD

  // ---- epilogue: bias + relu -> feat[g][b][pix*512+co], short4 stores ----
  float bias[8][4];
  #pragma unroll
  for (int mi = 0; mi < 8; ++mi)
    #pragma unroll
    for (int r = 0; r < 4; ++r)
      bias[mi][r] = conv_b[g*512 + mt*256 + wr*128 + mi*16 + l4*4 + r];
  #pragma unroll
  for (int nj = 0; nj < 4; ++nj) {
    int n = nt*256 + wc*64 + nj*16 + l15;
    unsigned bb = (unsigned)n / 36u;
    unsigned pix = (unsigned)n % 36u;
    size_t base = ((size_t)g*B_ + bb)*FCK + (size_t)pix*512;
    #pragma unroll
    for (int mi = 0; mi < 8; ++mi) {
      int co0 = mt*256 + wr*128 + mi*16 + l4*4;
      u16 q[4];
      #pragma unroll
      for (int r = 0; r < 4; ++r)
        q[r] = f2bf(fmaxf(acc[mi][nj][r] + bias[mi][r], 0.f));
      *(short4v*)(feat + base + co0) = *(short4v*)q;
    }
  }
}

// ---------------- FC: per-group [128 x 18432] x f32 fc_w, split-K 32 ----------------
// B staged inline from f32 fc_w (coalesced 256B runs in o), both-sides swizzle.
__global__ void __launch_bounds__(256) k_fc(const u16* __restrict__ feat,
                                            const float* __restrict__ fw,
                                            float* __restrict__ accum) {
  __shared__ __align__(16) u16 As[128*64];   // 16 KB
  __shared__ __align__(16) u16 Bs[160*64];   // 20 KB
  int sp = blockIdx.x;   // 0..31 k-split
  int g  = blockIdx.y;
  int tid = threadIdx.x;
  int lane = tid & 63, w = tid >> 6;
  int wr = w >> 1, wc = w & 1;
  int rl = lane >> 3, s = lane & 7;
  int l15 = lane & 15, l4 = lane >> 4;

  const u16* gA[4]; u16* lA[4];
  #pragma unroll
  for (int i = 0; i < 4; ++i) {
    int r = w*32 + i*8 + rl;
    int c = s ^ (r & 7);
    gA[i] = feat + ((size_t)g*B_ + r)*FCK + c*8;
    lA[i] = (u16*)As + (w*32 + i*8) * 64;
  }

  float4v acc[4][5];
  #pragma unroll
  for (int mi = 0; mi < 4; ++mi)
    #pragma unroll
    for (int nj = 0; nj < 5; ++nj) acc[mi][nj] = (float4v){0.f,0.f,0.f,0.f};

  int kbase = sp * 576;
  for (int stp = 0; stp < 9; ++stp) {
    int i0 = kbase + stp * 64;
    int pix = i0 >> 9;               // i0 / 512
    int cobase = i0 & 511;           // multiple of 64
    __syncthreads();
    #pragma unroll
    for (int i = 0; i < 4; ++i) load_lds16(gA[i] + i0, lA[i]);
    #pragma unroll
    for (int bit = 0; bit < 5; ++bit) {
      int idx = bit * 256 + tid;
      int il8 = idx / 160;           // k-slot 0..7
      int o   = idx - il8 * 160;     // 0..159
      u16 vals[8];
      if (o < 150) {
        const float* src = fw + ((size_t)g * FCK + (size_t)(cobase + il8 * 8) * 36 + pix) * 150 + o;
        #pragma unroll
        for (int j = 0; j < 8; ++j) vals[j] = f2bf(src[(size_t)j * 5400]);
      } else {
        #pragma unroll
        for (int j = 0; j < 8; ++j) vals[j] = 0;
      }
      *(short8*)((char*)Bs + o * 128 + ((il8 ^ (o & 7)) * 16)) = *(short8*)vals;
    }
    __syncthreads();

    short8 a[4][2], bf[5][2];
    #pragma unroll
    for (int kb = 0; kb < 2; ++kb) {
      #pragma unroll
      for (int mi = 0; mi < 4; ++mi) {
        int row = wr*64 + mi*16 + l15;
        int cb  = (kb*64 + l4*16) ^ ((row & 7) << 4);
        a[mi][kb] = *(const short8*)((const char*)As + row*128 + cb);
      }
      #pragma unroll
      for (int nj = 0; nj < 5; ++nj) {
        int row = wc*80 + nj*16 + l15;
        int cb  = (kb*64 + l4*16) ^ ((row & 7) << 4);
        bf[nj][kb] = *(const short8*)((const char*)Bs + row*128 + cb);
      }
    }
    #pragma unroll
    for (int kb = 0; kb < 2; ++kb)
      #pragma unroll
      for (int mi = 0; mi < 4; ++mi)
        #pragma unroll
        for (int nj = 0; nj < 5; ++nj)
          acc[mi][nj] = __builtin_amdgcn_mfma_f32_16x16x32_bf16(
              a[mi][kb], bf[nj][kb], acc[mi][nj], 0, 0, 0);
  }

  #pragma unroll
  for (int mi = 0; mi < 4; ++mi)
    #pragma unroll
    for (int r = 0; r < 4; ++r) {
      int brow = wr*64 + mi*16 + l4*4 + r;
      #pragma unroll
      for (int nj = 0; nj < 5; ++nj) {
        int o = wc*80 + nj*16 + l15;
        atomicAdd(&accum[((size_t)brow*20 + g)*160 + o], acc[mi][nj][r]);
      }
    }
}

__global__ void k_final(const float* __restrict__ accum, const float* __restrict__ fcb,
                        float* __restrict__ out) {
  int idx = blockIdx.x * 256 + threadIdx.x;     // 128*3000
  if (idx >= B_*3000) return;
  unsigned b = (unsigned)idx / 3000u;
  unsigned rem = (unsigned)idx % 3000u;
  unsigned g = rem / 150u, o = rem % 150u;
  out[idx] = fmaxf(accum[((size_t)b*20 + g)*160 + o] + fcb[g*150 + o], 0.f);
}

extern "C" void kernel_launch(void* const* d_in, const int* in_sizes, int n_in,
                              void* d_out, int out_size, void* d_ws, size_t ws_size,
                              hipStream_t stream) {
  const float* x      = (const float*)d_in[0];
  const float* y      = (const float*)d_in[1];
  const float* conv_w = (const float*)d_in[2];
  const float* conv_b = (const float*)d_in[3];
  const float* fc_w   = (const float*)d_in[4];
  const float* fc_b   = (const float*)d_in[5];
  float* out = (float*)d_out;

  char* ws = (char*)d_ws;
  size_t off = 0;
  u16* Wb   = (u16*)(ws + off); off += (size_t)10240 * K2 * 2;        // 94.4 MB
  u16* up3  = (u16*)(ws + off); off += (size_t)G_ * B_ * 64 * C_ * 2; // 167.8 MB
  u16* feat = (u16*)(ws + off); off += (size_t)G_ * B_ * FCK * 2;     // 94.4 MB
  u16* xT   = (u16*)(ws + off); off += (size_t)B_ * 196 * C_ * 2;     // 25.7 MB
  float* accum = (float*)(ws + off); off += (size_t)B_ * G_ * 160 * 4;// 1.6 MB
  int* cx = (int*)(ws + off); off += B_ * G_ * 4;
  int* cy = (int*)(ws + off); off += B_ * G_ * 4;

  k_pos<<<1, 128, 0, stream>>>(y, cx, cy);
  hipMemsetAsync(accum, 0, (size_t)B_ * G_ * 160 * 4, stream);
  k_pre1<<<3584, 256, 0, stream>>>(conv_w, Wb, x, xT);
  k_pre2<<<B_*G_, 256, 0, stream>>>(xT, cx, cy, up3);
  k_conv<<<720, 512, 0, stream>>>(Wb, up3, conv_b, feat);
  k_fc<<<dim3(32, 20), 256, 0, stream>>>(feat, fc_w, accum);
  k_final<<<(B_*3000 + 255)/256, 256, 0, stream>>>(accum, fc_b, out);
}